// Round 6
// baseline (156.664 us; speedup 1.0000x reference)
//
#include <hip/hip_runtime.h>

typedef __attribute__((ext_vector_type(4))) _Float16 f16x4;
typedef __attribute__((ext_vector_type(2))) __fp16 fp16x2;
typedef __attribute__((ext_vector_type(4))) float f32x4;

union U4 { f16x4 v; fp16x2 p[2]; };

__device__ __forceinline__ f16x4 cvt4(f32x4 a) {
  U4 u;
  u.p[0] = __builtin_amdgcn_cvt_pkrtz(a.x, a.y);
  u.p[1] = __builtin_amdgcn_cvt_pkrtz(a.z, a.w);
  return u.v;
}
__device__ __forceinline__ float dot4(f32x4 a, f32x4 b) {
  return a.x * b.x + a.y * b.y + a.z * b.z + a.w * b.w;
}

// Fully register-resident GCN. Each wave privately owns 16 batch rows.
// K=16 MFMA chain trick: mfma_f32_16x16x16_f16 B-frag layout (k=4q+j, col=c)
// == C-frag layout (row=4q+e, col=c), so layer l's accumulator feeds layer
// l+1's B operand directly after a packed f32->f16 convert. No LDS, no barriers.
__global__ __launch_bounds__(256, 2) void gcn_fused(
    const float* __restrict__ x,
    const float* __restrict__ W1, const float* __restrict__ B1,
    const float* __restrict__ W2, const float* __restrict__ B2,
    const float* __restrict__ W3, const float* __restrict__ B3,
    const float* __restrict__ W4, const float* __restrict__ B4,
    const float* __restrict__ fcw, const float* __restrict__ fcb,
    float* __restrict__ out)
{
  const int tid  = threadIdx.x;
  const int lane = tid & 63;
  const int w    = tid >> 6;
  const int c    = lane & 15;   // batch column within the wave's 16-row tile
  const int q    = lane >> 4;   // k-group / C row-group
  const int b    = blockIdx.x * 64 + w * 16 + c;  // this lane's batch row

  // inputs of node n: {self, nb0, nb1}
  const int IN[6][3] = {{0,1,2},{1,0,2},{2,1,3},{3,2,4},{4,3,5},{5,3,4}};
  const float* Ws[4] = {W1, W2, W3, W4};
  const float* Bs[4] = {B1, B2, B3, B4};

  // ---- stage x -> B-frag registers (h) + residual fc-dot partials ----
  f16x4 h[6][4];       // [node][k-chunk]: lane (c,q) holds feats 16t+4q+j of batch b
  float pacc[6];
  {
    const float* xr = x + (size_t)b * 384 + q * 4;
#pragma unroll
    for (int n = 0; n < 6; ++n) {
      float p = 0.f;
#pragma unroll
      for (int t = 0; t < 4; ++t) {
        f32x4 v  = *(const f32x4*)(xr + n * 64 + t * 16);
        f32x4 fw = *(const f32x4*)(fcw + n * 64 + t * 16 + q * 4);
        p += dot4(v, fw);
        h[n][t] = cvt4(v);
      }
      p += __shfl_xor(p, 16, 64);
      p += __shfl_xor(p, 32, 64);
      pacc[n] = p;   // dot(x[b,n,:], fcw[n,:]) in every q-lane
    }
  }

#pragma unroll
  for (int l = 0; l < 4; ++l) {
    const float cbv = (l < 2) ? (1.f / 3.f) : 0.25f;
    const float* Wl = Ws[l];
    // W as A-frags, pre-scaled by cb: wb[nt][kc] lane (c,q) = cb*W[16nt+c][16kc+4q+j]
    f16x4 wb[4][4];
#pragma unroll
    for (int nt = 0; nt < 4; ++nt)
#pragma unroll
      for (int kc = 0; kc < 4; ++kc) {
        f32x4 u = *(const f32x4*)(Wl + (nt * 16 + c) * 64 + kc * 16 + q * 4);
        u *= cbv;
        wb[nt][kc] = cvt4(u);
      }
    f32x4 bval[4];
#pragma unroll
    for (int nt = 0; nt < 4; ++nt)
      bval[nt] = *(const f32x4*)(Bs[l] + nt * 16 + q * 4);  // bias rows 16nt+4q+e

    f16x4 hn[6][4];
#pragma unroll
    for (int n = 0; n < 6; ++n) {
      f32x4 acc[4];
#pragma unroll
      for (int nt = 0; nt < 4; ++nt) acc[nt] = bval[nt];
#pragma unroll
      for (int mi = 0; mi < 3; ++mi) {
        const int m = IN[n][mi];
#pragma unroll
        for (int kc = 0; kc < 4; ++kc) {
          f16x4 bf = h[m][kc];
          if (l >= 2 && mi == 0) bf = bf + bf;   // self coeff ca = 2*cb (improved)
#pragma unroll
          for (int nt = 0; nt < 4; ++nt)
            acc[nt] = __builtin_amdgcn_mfma_f32_16x16x16f16(wb[nt][kc], bf, acc[nt], 0, 0, 0);
        }
      }
      if (l < 3) {
        // relu + f32->f16: becomes next layer's B-frags directly
#pragma unroll
        for (int nt = 0; nt < 4; ++nt) {
          f32x4 r;
#pragma unroll
          for (int e = 0; e < 4; ++e) r[e] = fmaxf(acc[nt][e], 0.f);
          hn[n][nt] = cvt4(r);
        }
      } else {
        // layer 4: relu + fc-dot in f32, never converts back
        float sv = 0.f;
#pragma unroll
        for (int nt = 0; nt < 4; ++nt) {
          f32x4 fw = *(const f32x4*)(fcw + n * 64 + nt * 16 + q * 4);
#pragma unroll
          for (int e = 0; e < 4; ++e) sv += fmaxf(acc[nt][e], 0.f) * fw[e];
        }
        sv += __shfl_xor(sv, 16, 64);
        sv += __shfl_xor(sv, 32, 64);
        const float vz = sv + pacc[n] + fcb[n];
        if (q == 0) out[(size_t)b * 6 + n] = 1.f / (1.f + __expf(-vz));
      }
    }
    if (l < 3) {
#pragma unroll
      for (int n = 0; n < 6; ++n)
#pragma unroll
        for (int t = 0; t < 4; ++t) h[n][t] = hn[n][t];
    }
  }
}

extern "C" void kernel_launch(void* const* d_in, const int* in_sizes, int n_in,
                              void* d_out, int out_size, void* d_ws, size_t ws_size,
                              hipStream_t stream) {
  const float* x   = (const float*)d_in[0];
  const float* W1  = (const float*)d_in[1];
  const float* B1  = (const float*)d_in[2];
  const float* W2  = (const float*)d_in[3];
  const float* B2  = (const float*)d_in[4];
  const float* W3  = (const float*)d_in[5];
  const float* B3  = (const float*)d_in[6];
  const float* W4  = (const float*)d_in[7];
  const float* B4  = (const float*)d_in[8];
  const float* fcw = (const float*)d_in[9];
  const float* fcb = (const float*)d_in[10];
  float* out = (float*)d_out;

  const int batch  = in_sizes[0] / 384;   // 131072
  const int blocks = batch / 64;          // 4 waves x 16 batch rows per block
  hipLaunchKernelGGL(gcn_fused, dim3(blocks), dim3(256), 0, stream,
                     x, W1, B1, W2, B2, W3, B3, W4, B4, fcw, fcb, out);
}